// Round 16
// baseline (49.818 us; speedup 1.0000x reference)
//
#include <hip/hip_runtime.h>
#include <hip/hip_bf16.h>

#define B_ 8
#define L_ 2048
#define D_ 256

typedef __bf16 bf16x8 __attribute__((ext_vector_type(8)));
typedef float f32x4 __attribute__((ext_vector_type(4)));

// round-to-nearest-even f32 -> bf16 (finite inputs)
static __device__ __forceinline__ unsigned short f2bf(float f) {
    unsigned int u = __builtin_bit_cast(unsigned int, f);
    unsigned int lsb = (u >> 16) & 1u;
    u += 0x7fffu + lsb;
    return (unsigned short)(u >> 16);
}

static __device__ __forceinline__ void gload_lds16(const void* g, void* l) {
    __builtin_amdgcn_global_load_lds(
        (const __attribute__((address_space(1))) unsigned int*)g,
        (__attribute__((address_space(3))) unsigned int*)l, 16, 0, 0);
}

// ---------------- prep (c only): A = bf16(c*cqw), s0 = c.cw + bias, s1 = c.qw
__global__ __launch_bounds__(256) void prep_kernel(
    const float* __restrict__ c,
    const float* __restrict__ cw, const float* __restrict__ qw,
    const float* __restrict__ cqw, const float* __restrict__ bias,
    unsigned short* __restrict__ Abf,
    float* __restrict__ s0, float* __restrict__ s1)
{
    const int wave = threadIdx.x >> 6;
    const int lane = threadIdx.x & 63;
    const int row  = blockIdx.x * 4 + wave;          // 0 .. B*L-1

    const float4 cv  = *(const float4*)(c   + (size_t)row * D_ + lane * 4);
    const float4 wc  = *(const float4*)(cw  + lane * 4);
    const float4 wq  = *(const float4*)(qw  + lane * 4);
    const float4 wcq = *(const float4*)(cqw + lane * 4);

    ushort4 av;
    av.x = f2bf(cv.x * wcq.x); av.y = f2bf(cv.y * wcq.y);
    av.z = f2bf(cv.z * wcq.z); av.w = f2bf(cv.w * wcq.w);
    *(ushort4*)(Abf + (size_t)row * D_ + lane * 4) = av;

    float p0 = cv.x * wc.x + cv.y * wc.y + cv.z * wc.z + cv.w * wc.w;
    float p1 = cv.x * wq.x + cv.y * wq.y + cv.z * wq.z + cv.w * wq.w;
    #pragma unroll
    for (int off = 32; off > 0; off >>= 1) {
        p0 += __shfl_down(p0, off);
        p1 += __shfl_down(p1, off);
    }
    if (lane == 0) { s0[row] = p0 + bias[0]; s1[row] = p1; }
}

// ---------------- GEMM: out[b,i,j] = s0[i]+s1[j] + sum_k A[i,k]*bf16(q[j,k]) -
// R13/R15 chassis (128x128, BK=32, 2-deep counted-vmcnt, skew, XCD swizzle)
// with Q FUSED: q staged as raw f32 via global_load_lds (8-slot row swizzle
// sl^(row&7)), converted to bf16 in registers at fragment-read time. Removes
// prep's q read + Qbf round-trip (~6us serial). LDS 48 KB -> 3 blocks/CU.
#define BM 128
#define BN 128
#define BK 32
#define NSTEP (D_ / BK)   // 8

__global__ __launch_bounds__(256) void gemm_kernel(
    const unsigned short* __restrict__ A, const float* __restrict__ q,
    const float* __restrict__ s0, const float* __restrict__ s1,
    float* __restrict__ out)
{
    __shared__ __align__(16) unsigned short As[2][BM * BK];   // 2 x 8 KiB
    __shared__ __align__(16) float          Qs[2][BM * BK];   // 2 x 16 KiB

    const int tid  = threadIdx.x;
    const int wave = tid >> 6;
    const int lane = tid & 63;

    // XCD-chunked bijective swizzle: batch k -> XCD k
    const int lin = blockIdx.x + (blockIdx.y << 4) + (blockIdx.z << 8); // 0..2047
    const int nl  = ((lin & 7) << 8) | (lin >> 3);
    const int b   = nl >> 8;
    const int brow = ((nl >> 4) & 15) * BM;
    const int bcol = (nl & 15) * BN;

    const unsigned short* Ab = A + ((size_t)b * L_ + brow) * D_;
    const float*          Qb = q + ((size_t)b * L_ + bcol) * D_;

    const int wr = wave >> 1;   // 0..1
    const int wc = wave & 1;    // 0..1

    f32x4 acc[4][4];
    #pragma unroll
    for (int m = 0; m < 4; ++m)
        #pragma unroll
        for (int n = 0; n < 4; ++n) acc[m][n] = {0.f, 0.f, 0.f, 0.f};

    // --- stage step s into buffer s&1: A 2 loads + Q 4 loads per thread ---
    // A rows: 64 B = 4 slots of 16B, swz slot^((row>>1)&3)  (bf16)
    // Q rows: 128 B = 8 slots of 16B, swz slot^(row&7)      (f32)
    auto stage = [&](int s) {
        const int k0 = s * BK;
        unsigned short* ab = &As[s & 1][0];
        float*          qs = &Qs[s & 1][0];
        #pragma unroll
        for (int i = 0; i < 2; ++i) {           // A: 512 slots
            const int sidx = i * 256 + tid;
            const int row  = sidx >> 2;
            const int sl   = sidx & 3;
            const int ksrc = k0 + ((sl ^ ((row >> 1) & 3)) << 3);   // bf16 units
            gload_lds16(Ab + (size_t)row * D_ + ksrc, ab + (i * 256 + wave * 64) * 8);
        }
        #pragma unroll
        for (int i = 0; i < 4; ++i) {           // Q: 1024 slots
            const int sidx = i * 256 + tid;
            const int row  = sidx >> 3;
            const int sl   = sidx & 7;
            const int ksrc = k0 + ((sl ^ (row & 7)) << 2);          // f32 units
            gload_lds16(Qb + (size_t)row * D_ + ksrc, qs + (i * 256 + wave * 64) * 4);
        }
    };

    // --- compute step t: 4 bf16 A-reads, 8 f32 Q-reads + cvt, 16 MFMA ---
    auto compute = [&](int t) {
        const unsigned short* ab = &As[t & 1][0];
        const float*          qs = &Qs[t & 1][0];
        bf16x8 af[4], qf[4];
        #pragma unroll
        for (int m = 0; m < 4; ++m) {
            const int row = wr * 64 + m * 16 + (lane & 15);
            const int idx = row * 32 + (((lane >> 4) ^ ((row >> 1) & 3)) << 3);
            af[m] = *(const bf16x8*)(ab + idx);
        }
        #pragma unroll
        for (int n = 0; n < 4; ++n) {
            const int row = wc * 64 + n * 16 + (lane & 15);
            const int sb  = (lane >> 4) * 2;
            const f32x4 lo = *(const f32x4*)(qs + row * 32 + (((sb    ) ^ (row & 7)) << 2));
            const f32x4 hi = *(const f32x4*)(qs + row * 32 + (((sb + 1) ^ (row & 7)) << 2));
            bf16x8 v;
            v[0] = (__bf16)lo[0]; v[1] = (__bf16)lo[1];
            v[2] = (__bf16)lo[2]; v[3] = (__bf16)lo[3];
            v[4] = (__bf16)hi[0]; v[5] = (__bf16)hi[1];
            v[6] = (__bf16)hi[2]; v[7] = (__bf16)hi[3];
            qf[n] = v;
        }
        __builtin_amdgcn_s_setprio(1);
        #pragma unroll
        for (int m = 0; m < 4; ++m)
            #pragma unroll
            for (int n = 0; n < 4; ++n)
                acc[m][n] = __builtin_amdgcn_mfma_f32_16x16x32_bf16(
                    af[m], qf[n], acc[m][n], 0, 0, 0);
        __builtin_amdgcn_s_setprio(0);
    };

    stage(0);

    // --- phase skew: first-round cohorts 1..3 wait 1.6/3.2/4.8us (100MHz) ---
    const int cohort = lin >> 8;             // 0..7
    if (cohort >= 1 && cohort <= 3) {
        const unsigned long long dl = (unsigned long long)cohort * 160ULL;
        const unsigned long long t0 = __builtin_amdgcn_s_memrealtime();
        while (__builtin_amdgcn_s_memrealtime() - t0 < dl)
            __builtin_amdgcn_s_sleep(2);
    }

#define STEP(T, VM) do {                                        \
        if ((T) + 1 < NSTEP) stage((T) + 1);                    \
        asm volatile("s_waitcnt vmcnt(" #VM ")" ::: "memory");  \
        __builtin_amdgcn_s_barrier();                           \
        asm volatile("" ::: "memory");                          \
        compute(T);                                             \
        asm volatile("" ::: "memory");                          \
        __builtin_amdgcn_s_barrier();                           \
        asm volatile("" ::: "memory");                          \
    } while (0)

    STEP(0, 6); STEP(1, 6); STEP(2, 6); STEP(3, 6);
    STEP(4, 6); STEP(5, 6); STEP(6, 6); STEP(7, 0);
#undef STEP

    // epilogue: + s0[i] (bias folded) + s1[j]
    const float* s0b = s0 + b * L_ + brow;
    const float* s1b = s1 + b * L_ + bcol;
    float s1v[4];
    #pragma unroll
    for (int n = 0; n < 4; ++n) s1v[n] = s1b[wc * 64 + n * 16 + (lane & 15)];
    float* outb = out + ((size_t)b * L_ + brow) * L_ + bcol;
    #pragma unroll
    for (int m = 0; m < 4; ++m) {
        #pragma unroll
        for (int r = 0; r < 4; ++r) {
            const int i = wr * 64 + m * 16 + (lane >> 4) * 4 + r;
            const float s0v = s0b[i];
            float* orow = outb + (size_t)i * L_;
            #pragma unroll
            for (int n = 0; n < 4; ++n)
                orow[wc * 64 + n * 16 + (lane & 15)] = acc[m][n][r] + s0v + s1v[n];
        }
    }
}

// ---------------- fallback (workspace too small): naive, correct, slow ------
__global__ void naive_kernel(const float* __restrict__ c, const float* __restrict__ q,
                             const float* __restrict__ cw, const float* __restrict__ qw,
                             const float* __restrict__ cqw, const float* __restrict__ bias,
                             float* __restrict__ out)
{
    const size_t total = (size_t)B_ * L_ * L_;
    for (size_t idx = (size_t)blockIdx.x * blockDim.x + threadIdx.x; idx < total;
         idx += (size_t)gridDim.x * blockDim.x) {
        const int b = (int)(idx / ((size_t)L_ * L_));
        const int rem = (int)(idx % ((size_t)L_ * L_));
        const int i = rem / L_, j = rem % L_;
        const float* ci = c + ((size_t)b * L_ + i) * D_;
        const float* cj = c + ((size_t)b * L_ + j) * D_;
        const float* qj = q + ((size_t)b * L_ + j) * D_;
        float acc = bias[0];
        for (int d = 0; d < D_; ++d)
            acc += ci[d] * cw[d] + cj[d] * qw[d] + ci[d] * cqw[d] * qj[d];
        out[idx] = acc;
    }
}

extern "C" void kernel_launch(void* const* d_in, const int* in_sizes, int n_in,
                              void* d_out, int out_size, void* d_ws, size_t ws_size,
                              hipStream_t stream) {
    const float* c    = (const float*)d_in[0];
    const float* q    = (const float*)d_in[1];
    const float* cw   = (const float*)d_in[2];
    const float* qw   = (const float*)d_in[3];
    const float* cqw  = (const float*)d_in[4];
    const float* bias = (const float*)d_in[5];
    float* out = (float*)d_out;

    const size_t bytesA = (size_t)B_ * L_ * D_ * 2;            // 8 MiB
    const size_t need   = bytesA + 2 * (size_t)B_ * L_ * 4;    // ~8.2 MiB

    if (ws_size >= need) {
        unsigned short* Abf = (unsigned short*)d_ws;
        float* s0 = (float*)((char*)d_ws + bytesA);
        float* s1 = s0 + (size_t)B_ * L_;
        prep_kernel<<<B_ * L_ / 4, 256, 0, stream>>>(c, cw, qw, cqw, bias,
                                                     Abf, s0, s1);
        dim3 grid(L_ / BN, L_ / BM, B_);
        gemm_kernel<<<grid, 256, 0, stream>>>(Abf, q, s0, s1, out);
    } else {
        naive_kernel<<<2048, 256, 0, stream>>>(c, q, cw, qw, cqw, bias, out);
    }
}

// Round 17
// 44.218 us; speedup vs baseline: 1.1266x; 1.1266x over previous
//
#include <hip/hip_runtime.h>
#include <hip/hip_bf16.h>

#define B_ 8
#define L_ 2048
#define D_ 256

typedef __bf16 bf16x8 __attribute__((ext_vector_type(8)));
typedef float f32x4 __attribute__((ext_vector_type(4)));

// round-to-nearest-even f32 -> bf16 (finite inputs)
static __device__ __forceinline__ unsigned short f2bf(float f) {
    unsigned int u = __builtin_bit_cast(unsigned int, f);
    unsigned int lsb = (u >> 16) & 1u;
    u += 0x7fffu + lsb;
    return (unsigned short)(u >> 16);
}

static __device__ __forceinline__ void gload_lds16(const void* g, void* l) {
    __builtin_amdgcn_global_load_lds(
        (const __attribute__((address_space(1))) unsigned int*)g,
        (__attribute__((address_space(3))) unsigned int*)l, 16, 0, 0);
}

// ---------------- prep: A = bf16(c*cqw), Q = bf16(q), s0 = c.cw + bias, s1 = c.qw
__global__ __launch_bounds__(256) void prep_kernel(
    const float* __restrict__ c, const float* __restrict__ q,
    const float* __restrict__ cw, const float* __restrict__ qw,
    const float* __restrict__ cqw, const float* __restrict__ bias,
    unsigned short* __restrict__ Abf, unsigned short* __restrict__ Qbf,
    float* __restrict__ s0, float* __restrict__ s1)
{
    const int wave = threadIdx.x >> 6;
    const int lane = threadIdx.x & 63;
    const int row  = blockIdx.x * 4 + wave;          // 0 .. B*L-1

    const float4 cv  = *(const float4*)(c   + (size_t)row * D_ + lane * 4);
    const float4 qv  = *(const float4*)(q   + (size_t)row * D_ + lane * 4);
    const float4 wc  = *(const float4*)(cw  + lane * 4);
    const float4 wq  = *(const float4*)(qw  + lane * 4);
    const float4 wcq = *(const float4*)(cqw + lane * 4);

    ushort4 av, qb;
    av.x = f2bf(cv.x * wcq.x); av.y = f2bf(cv.y * wcq.y);
    av.z = f2bf(cv.z * wcq.z); av.w = f2bf(cv.w * wcq.w);
    qb.x = f2bf(qv.x); qb.y = f2bf(qv.y);
    qb.z = f2bf(qv.z); qb.w = f2bf(qv.w);
    *(ushort4*)(Abf + (size_t)row * D_ + lane * 4) = av;
    *(ushort4*)(Qbf + (size_t)row * D_ + lane * 4) = qb;

    float p0 = cv.x * wc.x + cv.y * wc.y + cv.z * wc.z + cv.w * wc.w;
    float p1 = cv.x * wq.x + cv.y * wq.y + cv.z * wq.z + cv.w * wq.w;
    #pragma unroll
    for (int off = 32; off > 0; off >>= 1) {
        p0 += __shfl_down(p0, off);
        p1 += __shfl_down(p1, off);
    }
    if (lane == 0) { s0[row] = p0 + bias[0]; s1[row] = p1; }
}

// ---------------- GEMM: out[b,i,j] = s0[i]+s1[j] + sum_k A[i,k]*Q[j,k] -------
// BEST MEASURED (R13=44.55us / R15=44.69us): 128x128 tile, BK=32, 2-deep
// counted-vmcnt pipeline (LDS 32 KB), 4 blocks/CU (__launch_bounds__(256,4)).
// Stage(t+1) issued before compute(t); vmcnt(4) waits only for stage(t) --
// never drains. Phase skew 1.6us per first-round cohort (= store-burst drain
// time, dose-response measured R8/R9/R10). Batch->XCD bijective swizzle.
#define BM 128
#define BN 128
#define BK 32
#define NSTEP (D_ / BK)   // 8

__global__ __launch_bounds__(256, 4) void gemm_kernel(
    const unsigned short* __restrict__ A, const unsigned short* __restrict__ Q,
    const float* __restrict__ s0, const float* __restrict__ s1,
    float* __restrict__ out)
{
    __shared__ __align__(16) unsigned short As[2][BM * BK];   // 2 x 8 KiB
    __shared__ __align__(16) unsigned short Qs[2][BM * BK];   // 2 x 8 KiB

    const int tid  = threadIdx.x;
    const int wave = tid >> 6;
    const int lane = tid & 63;

    // XCD-chunked bijective swizzle: batch k -> XCD k
    const int lin = blockIdx.x + (blockIdx.y << 4) + (blockIdx.z << 8); // 0..2047
    const int nl  = ((lin & 7) << 8) | (lin >> 3);
    const int b   = nl >> 8;
    const int brow = ((nl >> 4) & 15) * BM;
    const int bcol = (nl & 15) * BN;

    const unsigned short* Ab = A + ((size_t)b * L_ + brow) * D_;
    const unsigned short* Qb = Q + ((size_t)b * L_ + bcol) * D_;

    const int wr = wave >> 1;   // 0..1
    const int wc = wave & 1;    // 0..1

    const f32x4 zero = {0.f, 0.f, 0.f, 0.f};
    f32x4 acc[4][4];
    #pragma unroll
    for (int m = 0; m < 4; ++m)
        #pragma unroll
        for (int n = 0; n < 4; ++n) acc[m][n] = zero;

    // --- stage step s into buffer s%2 (4 gload_lds/thread) ---
    auto stage = [&](int s) {
        const int k0 = s * BK;
        unsigned short* ab = &As[s & 1][0];
        unsigned short* qb = &Qs[s & 1][0];
        #pragma unroll
        for (int i = 0; i < 2; ++i) {
            const int sidx = i * 256 + wave * 64 + lane;   // slot index 0..511
            const int row  = sidx >> 2;                    // 0..127
            const int sl   = sidx & 3;
            const int ksrc = k0 + ((sl ^ ((row >> 1) & 3)) << 3);
            const int wbase = (i * 256 + wave * 64) * 8;   // ushort idx of wave base
            gload_lds16(Ab + (size_t)row * D_ + ksrc, ab + wbase);
            gload_lds16(Qb + (size_t)row * D_ + ksrc, qb + wbase);
        }
    };

    // --- compute step t from buffer t%2 (8 ds_read_b128 + 16 MFMA) ---
    auto compute = [&](int t) {
        const unsigned short* ab = &As[t & 1][0];
        const unsigned short* qb = &Qs[t & 1][0];
        bf16x8 af[4], qf[4];
        #pragma unroll
        for (int m = 0; m < 4; ++m) {
            const int row = wr * 64 + m * 16 + (lane & 15);
            const int idx = row * 32 + (((lane >> 4) ^ ((row >> 1) & 3)) << 3);
            af[m] = *(const bf16x8*)(ab + idx);
        }
        #pragma unroll
        for (int n = 0; n < 4; ++n) {
            const int row = wc * 64 + n * 16 + (lane & 15);
            const int idx = row * 32 + (((lane >> 4) ^ ((row >> 1) & 3)) << 3);
            qf[n] = *(const bf16x8*)(qb + idx);
        }
        __builtin_amdgcn_s_setprio(1);
        #pragma unroll
        for (int m = 0; m < 4; ++m)
            #pragma unroll
            for (int n = 0; n < 4; ++n)
                acc[m][n] = __builtin_amdgcn_mfma_f32_16x16x32_bf16(
                    af[m], qf[n], acc[m][n], 0, 0, 0);
        __builtin_amdgcn_s_setprio(0);
    };

    stage(0);

    // --- phase skew: first-round cohorts 1..3 wait 1.6/3.2/4.8us (100MHz) ---
    const int cohort = lin >> 8;             // 0..7
    if (cohort >= 1 && cohort <= 3) {
        const unsigned long long dl = (unsigned long long)cohort * 160ULL;
        const unsigned long long t0 = __builtin_amdgcn_s_memrealtime();
        while (__builtin_amdgcn_s_memrealtime() - t0 < dl)
            __builtin_amdgcn_s_sleep(2);
    }

#define STEP(T, VM) do {                                        \
        if ((T) + 1 < NSTEP) stage((T) + 1);                    \
        asm volatile("s_waitcnt vmcnt(" #VM ")" ::: "memory");  \
        __builtin_amdgcn_s_barrier();                           \
        asm volatile("" ::: "memory");                          \
        compute(T);                                             \
        asm volatile("" ::: "memory");                          \
        __builtin_amdgcn_s_barrier();                           \
        asm volatile("" ::: "memory");                          \
    } while (0)

    STEP(0, 4); STEP(1, 4); STEP(2, 4); STEP(3, 4);
    STEP(4, 4); STEP(5, 4); STEP(6, 4); STEP(7, 0);
#undef STEP

    // epilogue: + s0[i] (bias folded) + s1[j]
    const float* s0b = s0 + b * L_ + brow;
    const float* s1b = s1 + b * L_ + bcol;
    float s1v[4];
    #pragma unroll
    for (int n = 0; n < 4; ++n) s1v[n] = s1b[wc * 64 + n * 16 + (lane & 15)];
    float* outb = out + ((size_t)b * L_ + brow) * L_ + bcol;
    #pragma unroll
    for (int m = 0; m < 4; ++m) {
        #pragma unroll
        for (int r = 0; r < 4; ++r) {
            const int i = wr * 64 + m * 16 + (lane >> 4) * 4 + r;
            const float s0v = s0b[i];
            float* orow = outb + (size_t)i * L_;
            #pragma unroll
            for (int n = 0; n < 4; ++n)
                orow[wc * 64 + n * 16 + (lane & 15)] = acc[m][n][r] + s0v + s1v[n];
        }
    }
}

// ---------------- fallback (workspace too small): naive, correct, slow ------
__global__ void naive_kernel(const float* __restrict__ c, const float* __restrict__ q,
                             const float* __restrict__ cw, const float* __restrict__ qw,
                             const float* __restrict__ cqw, const float* __restrict__ bias,
                             float* __restrict__ out)
{
    const size_t total = (size_t)B_ * L_ * L_;
    for (size_t idx = (size_t)blockIdx.x * blockDim.x + threadIdx.x; idx < total;
         idx += (size_t)gridDim.x * blockDim.x) {
        const int b = (int)(idx / ((size_t)L_ * L_));
        const int rem = (int)(idx % ((size_t)L_ * L_));
        const int i = rem / L_, j = rem % L_;
        const float* ci = c + ((size_t)b * L_ + i) * D_;
        const float* cj = c + ((size_t)b * L_ + j) * D_;
        const float* qj = q + ((size_t)b * L_ + j) * D_;
        float acc = bias[0];
        for (int d = 0; d < D_; ++d)
            acc += ci[d] * cw[d] + cj[d] * qw[d] + ci[d] * cqw[d] * qj[d];
        out[idx] = acc;
    }
}

extern "C" void kernel_launch(void* const* d_in, const int* in_sizes, int n_in,
                              void* d_out, int out_size, void* d_ws, size_t ws_size,
                              hipStream_t stream) {
    const float* c    = (const float*)d_in[0];
    const float* q    = (const float*)d_in[1];
    const float* cw   = (const float*)d_in[2];
    const float* qw   = (const float*)d_in[3];
    const float* cqw  = (const float*)d_in[4];
    const float* bias = (const float*)d_in[5];
    float* out = (float*)d_out;

    const size_t bytesA = (size_t)B_ * L_ * D_ * 2;            // 8 MiB
    const size_t need   = 2 * bytesA + 2 * (size_t)B_ * L_ * 4; // ~16.1 MiB

    if (ws_size >= need) {
        unsigned short* Abf = (unsigned short*)d_ws;
        unsigned short* Qbf = (unsigned short*)((char*)d_ws + bytesA);
        float* s0 = (float*)((char*)d_ws + 2 * bytesA);
        float* s1 = s0 + (size_t)B_ * L_;
        prep_kernel<<<B_ * L_ / 4, 256, 0, stream>>>(c, q, cw, qw, cqw, bias,
                                                     Abf, Qbf, s0, s1);
        dim3 grid(L_ / BN, L_ / BM, B_);
        gemm_kernel<<<grid, 256, 0, stream>>>(Abf, Qbf, s0, s1, out);
    } else {
        naive_kernel<<<2048, 256, 0, stream>>>(c, q, cw, qw, cqw, bias, out);
    }
}